// Round 6
// baseline (216.766 us; speedup 1.0000x reference)
//
#include <hip/hip_runtime.h>

// Fused grouped-QKV GEMM: out[t,kv,g,d] = sum_e in[t,e]*W[e,kv,g,d] + bias
// M=64, K=4096, N=6144. fp32 in/out.
//
// R1-R5: every fused design pinned at 1.0-1.5 TB/s delivered -> concurrency/
// latency starvation (OccupancyPercent ~= waves/64; BW ~ waves*inflight).
// R6: two-stage.
//  (1) tswz: copy-shaped streaming kernel (3072 blocks, 1KB runs) converts
//      W fp32 [k][n] -> bf16 chunks pre-swizzled into MFMA B-frag lane
//      order: chunk(nt,ks)[lane] = 16B = W[ks*32+(lane>>4)*8+0..7][nt*16+
//      (lane&15)] k-pair-packed. GEMM B-loads become linear dwordx4.
//  (2) qkv_gemm: NO LDS, NO barriers, ~60 VGPR: wave job (nt,kq): 8 steps
//      of {1 B dwordx4 (contiguous stream) + 4 A frags (L2-hot g_abuf) +
//      4 MFMA}; atomic epilogue into bias-initialized out.

#define N_COLS 6144
#define K_DIM  4096
#define Q_SZ   (64 * 4096)
#define K_OFF  Q_SZ
#define V_OFF  (Q_SZ + 64 * 1024)
#define OUT_ELEMS 393216   // 64*6144
#define IN_ELEMS  262144   // 64*4096

typedef __bf16 bf16x8 __attribute__((ext_vector_type(8)));
typedef float  f32x4  __attribute__((ext_vector_type(4)));
typedef unsigned int u32x4 __attribute__((ext_vector_type(4)));

__device__ unsigned short g_abuf[IN_ELEMS];      // bf16 input copy
__device__ u32x4 g_wswz[384 * 128 * 64];         // 50.3MB swizzled bf16 W

__device__ __forceinline__ unsigned short f2bf_rne(float f) {
    unsigned int u = __float_as_uint(f);
    u += 0x7FFFu + ((u >> 16) & 1u);
    return (unsigned short)(u >> 16);
}

__device__ __forceinline__ unsigned int pack_pair(float lo, float hi) {
    return ((unsigned int)f2bf_rne(hi) << 16) | f2bf_rne(lo);
}

__device__ __forceinline__ int out_index(int t, int n) {
    const int kv = n / 768;
    const int g  = (n >> 7) % 6;
    const int d  = n & 127;
    if (g < 4)  return t * 4096 + kv * 512 + g * 128 + d;   // q
    if (g == 4) return K_OFF + t * 1024 + kv * 128 + d;     // k
    return V_OFF + t * 1024 + kv * 128 + d;                 // v
}

// out <- bias broadcast; g_abuf <- bf16(in)
__global__ __launch_bounds__(256)
void init_kernel(const float* __restrict__ in, const float* __restrict__ bias,
                 float* __restrict__ out) {
    const int i = blockIdx.x * 256 + threadIdx.x;
    if (i < IN_ELEMS) g_abuf[i] = f2bf_rne(in[i]);
    if (i < OUT_ELEMS) {
        const int d   = i & 127;
        const int g   = (i >> 7) % 6;
        const int kvt = i / 768;
        const int kv  = kvt & 7;
        const int t   = kvt >> 3;
        out[out_index(t, kv * 768 + g * 128 + d)] = bias[(kv * 6 + g) * 128 + d];
    }
}

// Streaming convert+swizzle: tile = 32k x 256n per block, 3072 blocks.
// Reads: 32 x 1KB rows (copy-identical). Writes: 16 x 1KB chunks (linear).
__global__ __launch_bounds__(256)
void tswz(const float* __restrict__ w) {
    __shared__ float Ls[32][256];   // 32KB fp32 tile

    const int bid = blockIdx.x;
    const int n0  = (bid % 24) * 256;   // adjacent blocks sweep n, then k
    const int ks  = bid / 24;           // 0..127 (32-k band)
    const int k0  = ks * 32;
    const int tid = threadIdx.x;

    // load 2048 x 16B slots linearly: slot -> (row = slot/64, col4 = slot%64)
    #pragma unroll
    for (int i = 0; i < 8; ++i) {
        const int slot = i * 256 + tid;
        const int row  = slot >> 6;
        const int col4 = slot & 63;
        *(float4*)&Ls[row][col4 * 4] =
            *(const float4*)(w + (size_t)(k0 + row) * N_COLS + n0 + col4 * 4);
    }
    __syncthreads();

    const int lane = tid & 63;
    const int l15  = lane & 15;
    const int kblk = lane >> 4;
    #pragma unroll
    for (int p = 0; p < 4; ++p) {
        const int ci = p * 4 + (tid >> 6);          // chunk 0..15 within tile
        const int n  = ci * 16 + l15;
        u32x4 cell;
        #pragma unroll
        for (int j2 = 0; j2 < 4; ++j2) {
            const int k2 = kblk * 8 + 2 * j2;
            cell[j2] = pack_pair(Ls[k2][n], Ls[k2 + 1][n]);
        }
        const int nt = (n0 >> 4) + ci;
        g_wswz[(((size_t)nt * 128 + ks) << 6) + lane] = cell;
    }
}

// Barrier-free LDS-free GEMM over the swizzled weight.
__global__ __launch_bounds__(256, 6)
void qkv_gemm(float* __restrict__ out) {
    const int tid  = threadIdx.x;
    const int bid  = blockIdx.x;        // 1536
    const int nt   = bid >> 2;          // 0..383 (16-wide n tile)
    const int wid  = tid >> 6;
    const int kq   = (bid & 3) * 4 + wid;   // 0..15 (256-wide k split)
    const int lane = tid & 63;
    const int l15  = lane & 15;
    const int kblk = lane >> 4;

    const u32x4* bp = &g_wswz[(((size_t)nt * 128 + kq * 8) << 6) + lane];
    const unsigned short* ab = g_abuf + l15 * K_DIM + kq * 256 + kblk * 8;

    f32x4 acc[4] = {{0.f,0.f,0.f,0.f},{0.f,0.f,0.f,0.f},
                    {0.f,0.f,0.f,0.f},{0.f,0.f,0.f,0.f}};

    u32x4 bcur = bp[0];
    #pragma unroll
    for (int s = 0; s < 8; ++s) {
        u32x4 bnext;
        if (s < 7) bnext = bp[(s + 1) << 6];   // next 1KB of the linear stream

        const unsigned short* ap = ab + s * 32;
        const u32x4 a0 = *(const u32x4*)(ap);
        const u32x4 a1 = *(const u32x4*)(ap + 16 * K_DIM);
        const u32x4 a2 = *(const u32x4*)(ap + 32 * K_DIM);
        const u32x4 a3 = *(const u32x4*)(ap + 48 * K_DIM);

        const bf16x8 bf = __builtin_bit_cast(bf16x8, bcur);
        acc[0] = __builtin_amdgcn_mfma_f32_16x16x32_bf16(
                     __builtin_bit_cast(bf16x8, a0), bf, acc[0], 0, 0, 0);
        acc[1] = __builtin_amdgcn_mfma_f32_16x16x32_bf16(
                     __builtin_bit_cast(bf16x8, a1), bf, acc[1], 0, 0, 0);
        acc[2] = __builtin_amdgcn_mfma_f32_16x16x32_bf16(
                     __builtin_bit_cast(bf16x8, a2), bf, acc[2], 0, 0, 0);
        acc[3] = __builtin_amdgcn_mfma_f32_16x16x32_bf16(
                     __builtin_bit_cast(bf16x8, a3), bf, acc[3], 0, 0, 0);
        bcur = bnext;
    }

    // epilogue: n = nt*16 + l15 (C/D col), t = t16*16 + kblk*4 + r (row)
    const int n = nt * 16 + l15;
    #pragma unroll
    for (int t16 = 0; t16 < 4; ++t16)
        #pragma unroll
        for (int r = 0; r < 4; ++r)
            atomicAdd(&out[out_index(t16 * 16 + kblk * 4 + r, n)], acc[t16][r]);
}

extern "C" void kernel_launch(void* const* d_in, const int* in_sizes, int n_in,
                              void* d_out, int out_size, void* d_ws, size_t ws_size,
                              hipStream_t stream) {
    const float* in   = (const float*)d_in[0];  // [64, 4096]
    const float* w    = (const float*)d_in[1];  // [4096, 8, 6, 128]
    const float* bias = (const float*)d_in[2];  // [8, 6, 128]
    float* out = (float*)d_out;

    init_kernel<<<(OUT_ELEMS + 255) / 256, 256, 0, stream>>>(in, bias, out);
    tswz<<<3072, 256, 0, stream>>>(w);
    qkv_gemm<<<1536, 256, 0, stream>>>(out);
}

// Round 7
// 163.876 us; speedup vs baseline: 1.3227x; 1.3227x over previous
//
#include <hip/hip_runtime.h>

// Fused grouped-QKV GEMM: out[t,kv,g,d] = sum_e in[t,e]*W[e,kv,g,d] + bias
// M=64, K=4096, N=6144. fp32 in/out.
//
// R1-R6: register-destined W loads consumed by MFMA let the compiler cap
// outstanding loads/wave at ~1-2 -> 1.5 TB/s latency wall. Harness fill
// kernel proves 6.8 TB/s is reachable. R7: m97-style global_load_lds
// staging -- a 16KB W-tile is issued as VGPR-free DMA (16 wave-instrs in
// flight) before one barrier drain; m97 sustains >13 TB/s with this
// structure. A-frags prefetched fp32 from L2-hot `in` in the same window.
// fp32 partials to d_ws + separate reduce (no atomics).

#define N_COLS 6144
#define K_DIM  4096
#define Q_SZ   (64 * 4096)
#define K_OFF  Q_SZ
#define V_OFF  (Q_SZ + 64 * 1024)
#define OUT_ELEMS 393216   // 64*6144
#define NT     48          // n-tiles of 128
#define KSPLIT 16          // 256 k per block -> 768 blocks
#define BK     32
#define TILES  8           // 256/32

typedef __bf16 bf16x8 __attribute__((ext_vector_type(8)));
typedef float  f32x4  __attribute__((ext_vector_type(4)));
typedef unsigned int u32x4 __attribute__((ext_vector_type(4)));

__device__ __forceinline__ unsigned short f2bf_rne(float f) {
    unsigned int u = __float_as_uint(f);
    u += 0x7FFFu + ((u >> 16) & 1u);
    return (unsigned short)(u >> 16);
}

__device__ __forceinline__ unsigned int pack_pair(float lo, float hi) {
    return ((unsigned int)f2bf_rne(hi) << 16) | f2bf_rne(lo);
}

__device__ __forceinline__ int out_index(int t, int n) {
    const int kv = n / 768;
    const int g  = (n >> 7) % 6;
    const int d  = n & 127;
    if (g < 4)  return t * 4096 + kv * 512 + g * 128 + d;   // q
    if (g == 4) return K_OFF + t * 1024 + kv * 128 + d;     // k
    return V_OFF + t * 1024 + kv * 128 + d;                 // v
}

// async global->LDS, 16B per lane (wave-uniform LDS base + lane*16)
#define GLDS(gp, lp) __builtin_amdgcn_global_load_lds(                        \
    (const __attribute__((address_space(1))) void*)(gp),                      \
    (__attribute__((address_space(3))) void*)(lp), 16, 0, 0)

__global__ __launch_bounds__(256, 4)
void qkv_gemm(const float* __restrict__ in, const float* __restrict__ w,
              float* __restrict__ part) {
    __shared__ float Ws[BK * 128];   // 16KB fp32 W-tile, [k][n] k-major

    const int tid  = threadIdx.x;
    const int nt   = blockIdx.x % NT;    // adjacent blocks: adjacent n, same k
    const int kq   = blockIdx.x / NT;
    const int n0   = nt * 128;
    const int k0   = kq * 256;
    const int wid  = tid >> 6;
    const int lane = tid & 63;
    const int l15  = lane & 15;
    const int kblk = lane >> 4;

    f32x4 acc[2][4];
    #pragma unroll
    for (int a = 0; a < 2; ++a)
        #pragma unroll
        for (int b = 0; b < 4; ++b) acc[a][b] = (f32x4){0.f, 0.f, 0.f, 0.f};

    #pragma unroll 1
    for (int s = 0; s < TILES; ++s) {
        const int kc = k0 + s * BK;

        // stage W tile: 16KB as 1024 16B slots, slot u -> row k=u>>5, n-chunk u&31.
        // All 16 wave-instrs (DMA, no VGPR dest) in flight before one drain.
        const float* wr = w + (size_t)kc * N_COLS + n0;
        #pragma unroll
        for (int r = 0; r < 4; ++r) {
            const int u = r * 256 + tid;
            GLDS(wr + (size_t)(u >> 5) * N_COLS + (u & 31) * 4, &Ws[u * 4]);
        }

        // A-frag prefetch (fp32, L2-hot 1MB input) in the same issue window
        float4 alo[4], ahi[4];
        #pragma unroll
        for (int mi = 0; mi < 4; ++mi) {
            const float* ap = in + (size_t)(mi * 16 + l15) * K_DIM + kc + kblk * 8;
            alo[mi] = *(const float4*)ap;
            ahi[mi] = *(const float4*)(ap + 4);
        }

        __syncthreads();   // vmcnt(0) drain: Ws + A loads complete

        // pack A-frags: element j = k-offset j (k ascending, pairs lo/hi)
        u32x4 af[4];
        #pragma unroll
        for (int mi = 0; mi < 4; ++mi) {
            af[mi][0] = pack_pair(alo[mi].x, alo[mi].y);
            af[mi][1] = pack_pair(alo[mi].z, alo[mi].w);
            af[mi][2] = pack_pair(ahi[mi].x, ahi[mi].y);
            af[mi][3] = pack_pair(ahi[mi].z, ahi[mi].w);
        }

        // wave wid owns n-frags {2*wid, 2*wid+1}
        #pragma unroll
        for (int nfi = 0; nfi < 2; ++nfi) {
            const int nb = (wid * 2 + nfi) * 16 + l15;
            float bf[8];
            #pragma unroll
            for (int j = 0; j < 8; ++j)
                bf[j] = Ws[(kblk * 8 + j) * 128 + nb];   // ~4-way banks (1.58x)
            u32x4 bu;
            #pragma unroll
            for (int j2 = 0; j2 < 4; ++j2)
                bu[j2] = pack_pair(bf[2 * j2], bf[2 * j2 + 1]);

            const bf16x8 bv = __builtin_bit_cast(bf16x8, bu);
            #pragma unroll
            for (int mi = 0; mi < 4; ++mi)
                acc[nfi][mi] = __builtin_amdgcn_mfma_f32_16x16x32_bf16(
                    __builtin_bit_cast(bf16x8, af[mi]), bv, acc[nfi][mi], 0, 0, 0);
        }

        __syncthreads();   // frag reads done before next tile overwrite
    }

    // partials: C/D col = l15 (n), row = kblk*4 + r (token within m-frag)
    float* pb = part + (size_t)kq * OUT_ELEMS;
    #pragma unroll
    for (int nfi = 0; nfi < 2; ++nfi) {
        const int n = n0 + (wid * 2 + nfi) * 16 + l15;
        #pragma unroll
        for (int mi = 0; mi < 4; ++mi) {
            #pragma unroll
            for (int r = 0; r < 4; ++r) {
                const int t = mi * 16 + kblk * 4 + r;
                pb[(size_t)t * N_COLS + n] = acc[nfi][mi][r];
            }
        }
    }
}

// sum KSPLIT partials + bias, scatter to q|k|v
__global__ __launch_bounds__(256)
void qkv_reduce(const float* __restrict__ part, const float* __restrict__ bias,
                float* __restrict__ out) {
    const int i = blockIdx.x * 256 + threadIdx.x;   // 0..393215
    const int t = i / N_COLS;
    const int n = i % N_COLS;
    float s = bias[n];
    #pragma unroll
    for (int kq = 0; kq < KSPLIT; ++kq)
        s += part[(size_t)kq * OUT_ELEMS + i];
    out[out_index(t, n)] = s;
}

extern "C" void kernel_launch(void* const* d_in, const int* in_sizes, int n_in,
                              void* d_out, int out_size, void* d_ws, size_t ws_size,
                              hipStream_t stream) {
    const float* in   = (const float*)d_in[0];  // [64, 4096]
    const float* w    = (const float*)d_in[1];  // [4096, 8, 6, 128]
    const float* bias = (const float*)d_in[2];  // [8, 6, 128]
    float* out  = (float*)d_out;
    float* part = (float*)d_ws;                 // 16 * 1.57MB = 25.2MB fp32

    qkv_gemm<<<NT * KSPLIT, 256, 0, stream>>>(in, w, part);
    qkv_reduce<<<OUT_ELEMS / 256, 256, 0, stream>>>(part, bias, out);
}